// Round 1
// baseline (8370.400 us; speedup 1.0000x reference)
//
#include <hip/hip_runtime.h>

// Problem constants (from setup_inputs: B=16, N=16384, D=128, S=N/4)
#define BATCH    16
#define NPTS     16384
#define NSAMP    4096
#define NTHREADS 1024
#define PPT      16      // NPTS / NTHREADS, points per thread (contiguous)

// -----------------------------------------------------------------------------
// FPS kernel: one block per batch. Each thread keeps PPT contiguous points and
// their running min-distance in registers. Reproduces the reference exactly:
//   dist = min(dist, (x-cx)^2 + (y-cy)^2 + (z-cz)^2)   [fp32, no FMA]
//   next = argmax(dist)  with first-index tie-break
// Selected indices are recorded in an LDS bitmap; the kernel tail converts the
// bitmap to an ascending (sorted) index list via a block prefix scan.
// -----------------------------------------------------------------------------
__global__ __launch_bounds__(NTHREADS) void fps_kernel(
    const float* __restrict__ xyz, int* __restrict__ sorted_idx)
{
    __shared__ unsigned s_bitmap[NPTS / 32];   // 512 words = 2 KiB
    __shared__ float s_wv[16];                 // per-wave max value
    __shared__ int   s_wi[16];                 // per-wave candidate global idx
    __shared__ float s_wcx[16], s_wcy[16], s_wcz[16]; // candidate coords
    __shared__ int   s_wt[16];                 // per-wave scan totals

    const int tid  = threadIdx.x;
    const int lane = tid & 63;
    const int wid  = tid >> 6;
    const int b    = blockIdx.x;

    // zero the bitmap
    for (int i = tid; i < NPTS / 32; i += NTHREADS) s_bitmap[i] = 0u;

    // load this thread's points (contiguous block of PPT points) into registers
    float px[PPT], py[PPT], pz[PPT], pd[PPT];
    {
        const float* xb = xyz + ((size_t)b * NPTS + (size_t)tid * PPT) * 3;
        #pragma unroll
        for (int k = 0; k < PPT; ++k) {
            px[k] = xb[k * 3 + 0];
            py[k] = xb[k * 3 + 1];
            pz[k] = xb[k * 3 + 2];
            pd[k] = 1e10f;     // BIG, matches reference init
        }
    }

    // initial farthest = index 0; its coords are the first centroid
    float cx = xyz[(size_t)b * NPTS * 3 + 0];
    float cy = xyz[(size_t)b * NPTS * 3 + 1];
    float cz = xyz[(size_t)b * NPTS * 3 + 2];
    if (tid == 0) s_bitmap[0] = 1u;   // thread 0 zeroed word 0 above (same thread)
    __syncthreads();

    for (int s = 0; s < NSAMP - 1; ++s) {
        // --- phase A: distance update + per-thread max (exact fp32, no FMA) ---
        float best = -1.0f;
        #pragma unroll
        for (int k = 0; k < PPT; ++k) {
            float dx = __fsub_rn(px[k], cx);
            float dy = __fsub_rn(py[k], cy);
            float dz = __fsub_rn(pz[k], cz);
            float d  = __fadd_rn(__fadd_rn(__fmul_rn(dx, dx), __fmul_rn(dy, dy)),
                                 __fmul_rn(dz, dz));
            float nd = fminf(pd[k], d);
            pd[k] = nd;
            best = fmaxf(best, nd);
        }
        // wave max
        float wv = best;
        #pragma unroll
        for (int off = 1; off < 64; off <<= 1)
            wv = fmaxf(wv, __shfl_xor(wv, off));
        if (lane == 0) s_wv[wid] = wv;
        __syncthreads();   // b1

        // --- phase B: block max, then per-wave candidate with tie-break ---
        float m;
        {
            float v = s_wv[lane & 15];
            #pragma unroll
            for (int off = 1; off < 16; off <<= 1)
                v = fmaxf(v, __shfl_xor(v, off));
            m = v;   // uniform across block
        }
        unsigned long long bal = __ballot(best == m);
        if (bal != 0ull) {
            if (lane == __ffsll((unsigned long long)bal) - 1) {
                // smallest local k with pd[k] == m  (first-index tie-break)
                int kk = 0;
                #pragma unroll
                for (int k = PPT - 1; k >= 0; --k) if (pd[k] == m) kk = k;
                // static extraction of coords (runtime kk -> cndmask chain, no scratch)
                float ax = 0.f, ay = 0.f, az = 0.f;
                #pragma unroll
                for (int k = 0; k < PPT; ++k)
                    if (k == kk) { ax = px[k]; ay = py[k]; az = pz[k]; }
                s_wi[wid]  = tid * PPT + kk;
                s_wcx[wid] = ax; s_wcy[wid] = ay; s_wcz[wid] = az;
            }
        } else if (lane == 0) {
            s_wi[wid] = 0x7FFFFFFF;
        }
        __syncthreads();   // b2

        // --- phase C: global winner = min candidate index (exact tie-break) ---
        int gi = s_wi[lane & 15];
        int wi = lane & 15;
        #pragma unroll
        for (int off = 1; off < 16; off <<= 1) {
            int og = __shfl_xor(gi, off);
            int ow = __shfl_xor(wi, off);
            if (og < gi) { gi = og; wi = ow; }
        }
        // all lanes/waves agree on (gi, wi)
        cx = s_wcx[wi]; cy = s_wcy[wi]; cz = s_wcz[wi];
        if (tid == 0) s_bitmap[gi >> 5] |= (1u << (gi & 31));
    }

    // --- tail: bitmap -> ascending index list via block prefix scan ---
    __syncthreads();
    unsigned word = s_bitmap[tid >> 1];
    unsigned half = (tid & 1) ? (word >> 16) : (word & 0xFFFFu);
    int cnt = __popc(half);
    int inc = cnt;
    #pragma unroll
    for (int off = 1; off < 64; off <<= 1) {
        int n = __shfl_up(inc, off);
        if (lane >= off) inc += n;
    }
    if (lane == 63) s_wt[wid] = inc;
    __syncthreads();
    int base = inc - cnt;
    for (int w = 0; w < wid; ++w) base += s_wt[w];
    int* sb = sorted_idx + (size_t)b * NSAMP;
    int pos = base;
    #pragma unroll
    for (int k = 0; k < PPT; ++k)
        if ((half >> k) & 1) { sb[pos++] = tid * PPT + k; }
}

// -----------------------------------------------------------------------------
// Gather kernel: one wave per sampled row.
//   out0 = new_xyz        [B,S,3]
//   out1 = concat(xyz, points) [B,S,1,131]
//   out2 = points_res gathered [B,S,128]
// -----------------------------------------------------------------------------
__global__ void gather_kernel(
    const float* __restrict__ xyz, const float* __restrict__ points,
    const float* __restrict__ pres, const int* __restrict__ sorted_idx,
    float* __restrict__ out0, float* __restrict__ out1, float* __restrict__ out2)
{
    int gw   = (int)((blockIdx.x * (unsigned)blockDim.x + threadIdx.x) >> 6);
    int lane = threadIdx.x & 63;
    if (gw >= BATCH * NSAMP) return;
    int b = gw >> 12;               // NSAMP == 4096
    int i = sorted_idx[gw];

    const float* xs = xyz    + ((size_t)b * NPTS + i) * 3;
    const float* ps = points + ((size_t)b * NPTS + i) * 128;
    const float* rs = pres   + ((size_t)b * NPTS + i) * 128;

    if (lane < 3) out0[(size_t)gw * 3 + lane] = xs[lane];

    float* o1 = out1 + (size_t)gw * 131;
    #pragma unroll
    for (int j = 0; j < 3; ++j) {
        int c = lane + 64 * j;
        if (c < 131) o1[c] = (c < 3) ? xs[c] : ps[c - 3];
    }

    const float2* r2 = (const float2*)rs;
    float2* o2 = (float2*)(out2 + (size_t)gw * 128);
    o2[lane] = r2[lane];
}

extern "C" void kernel_launch(void* const* d_in, const int* in_sizes, int n_in,
                              void* d_out, int out_size, void* d_ws, size_t ws_size,
                              hipStream_t stream)
{
    const float* xyz    = (const float*)d_in[0];
    const float* points = (const float*)d_in[1];
    const float* pres   = (const float*)d_in[2];

    float* out  = (float*)d_out;
    float* out0 = out;                                     // B*S*3
    float* out1 = out0 + (size_t)BATCH * NSAMP * 3;        // B*S*131
    float* out2 = out1 + (size_t)BATCH * NSAMP * 131;      // B*S*128

    int* sorted = (int*)d_ws;   // B*S ints = 256 KiB scratch

    fps_kernel<<<BATCH, NTHREADS, 0, stream>>>(xyz, sorted);

    int total_threads = BATCH * NSAMP * 64;   // one wave per sampled row
    int threads = 256;
    int blocks  = total_threads / threads;
    gather_kernel<<<blocks, threads, 0, stream>>>(xyz, points, pres, sorted,
                                                  out0, out1, out2);
}

// Round 2
// 7194.875 us; speedup vs baseline: 1.1634x; 1.1634x over previous
//
#include <hip/hip_runtime.h>

// Problem constants (from setup_inputs: B=16, N=16384, D=128, S=N/4)
#define BATCH    16
#define NPTS     16384
#define NSAMP    4096
#define NTHREADS 1024
#define PPT      16      // NPTS / NTHREADS, points per thread (contiguous)

// DPP helper: move with self-preserving old (disabled lanes keep own value)
template<int CTRL, int RM>
__device__ __forceinline__ unsigned dpp_mov(unsigned v) {
    return (unsigned)__builtin_amdgcn_update_dpp((int)v, (int)v, CTRL, RM, 0xF, false);
}

// One step of a (hi,lo) u64-key max reduction via DPP.
// hi = dist bits (non-negative fp32 -> uint order == float order)
// lo = ~global_index (max key => min index on dist ties)
template<int CTRL, int RM>
__device__ __forceinline__ void red_step(unsigned& hi, unsigned& lo) {
    unsigned h2 = dpp_mov<CTRL, RM>(hi);
    unsigned l2 = dpp_mov<CTRL, RM>(lo);
    bool take = (h2 > hi) || (h2 == hi && l2 > lo);
    hi = take ? h2 : hi;
    lo = take ? l2 : lo;
}

// -----------------------------------------------------------------------------
// FPS kernel: one block per batch. Points + running min-dist live in registers.
// Exact reference semantics: dist = min(dist, (x-cx)^2+(y-cy)^2+(z-cz)^2)
// (fp32, no FMA, (xx+yy)+zz association), argmax with first-index tie-break.
// Per iteration: ONE barrier; wave-level DPP pair-reduce (no LDS shuffles);
// cross-wave combine via a single ds_max_u64 per wave; centroid re-fetched
// from global (L2-resident) via a uniform scalar load.
// -----------------------------------------------------------------------------
__global__ __launch_bounds__(NTHREADS) void fps_kernel(
    const float* __restrict__ xyz, int* __restrict__ sorted_idx)
{
    __shared__ unsigned s_bitmap[NPTS / 32];       // 512 words = 2 KiB
    __shared__ unsigned long long s_slot[4];       // rotating winner slots
    __shared__ int s_wt[16];                       // tail scan totals

    const int tid  = threadIdx.x;
    const int lane = tid & 63;
    const int wid  = tid >> 6;
    const int b    = blockIdx.x;

    for (int i = tid; i < NPTS / 32; i += NTHREADS) s_bitmap[i] = 0u;
    if (tid < 4) s_slot[tid] = 0ull;

    const float* xb = xyz + (size_t)b * NPTS * 3;

    // load this thread's PPT contiguous points into registers
    float px[PPT], py[PPT], pz[PPT], pd[PPT];
    {
        const float* p = xb + (size_t)tid * PPT * 3;
        #pragma unroll
        for (int k = 0; k < PPT; ++k) {
            px[k] = p[3 * k + 0];
            py[k] = p[3 * k + 1];
            pz[k] = p[3 * k + 2];
            pd[k] = 1e10f;   // BIG, matches reference init
        }
    }

    // initial farthest = index 0
    float cx = xb[0], cy = xb[1], cz = xb[2];
    if (tid == 0) s_bitmap[0] = 1u;
    __syncthreads();

    for (int s = 0; s < NSAMP - 1; ++s) {
        // --- phase A: exact distance update + inline per-thread argmax ---
        float bv = -1.0f;
        int   bk = 0;
        #pragma unroll
        for (int k = 0; k < PPT; ++k) {
            float dx = __fsub_rn(px[k], cx);
            float dy = __fsub_rn(py[k], cy);
            float dz = __fsub_rn(pz[k], cz);
            float d  = __fadd_rn(__fadd_rn(__fmul_rn(dx, dx), __fmul_rn(dy, dy)),
                                 __fmul_rn(dz, dz));
            float nd = fminf(pd[k], d);
            pd[k] = nd;
            if (nd > bv) { bv = nd; bk = k; }   // strict > keeps smallest k
        }

        // --- wave-level DPP pair-reduce of the packed key (result in lane 63) ---
        unsigned hi = __float_as_uint(bv);
        unsigned lo = ~(unsigned)(tid * PPT + bk);
        red_step<0x111, 0xF>(hi, lo);   // row_shr:1
        red_step<0x112, 0xF>(hi, lo);   // row_shr:2
        red_step<0x114, 0xF>(hi, lo);   // row_shr:4
        red_step<0x118, 0xF>(hi, lo);   // row_shr:8
        red_step<0x142, 0xA>(hi, lo);   // row_bcast:15 (rows 1,3)
        red_step<0x143, 0xC>(hi, lo);   // row_bcast:31 (rows 2,3)

        if (lane == 63)
            atomicMax(&s_slot[s & 3], ((unsigned long long)hi << 32) | (unsigned long long)lo);

        __syncthreads();   // the ONLY barrier per iteration

        unsigned long long key = s_slot[s & 3];
        unsigned gi = ~(unsigned)key;                      // winner index in [0,NPTS)
        int g = __builtin_amdgcn_readfirstlane((int)gi);   // force SGPR / scalar load

        cx = xb[3 * g + 0];
        cy = xb[3 * g + 1];
        cz = xb[3 * g + 2];

        if (tid == 0) {
            s_slot[(s + 3) & 3] = 0ull;                    // reset slot reused at s+3
            s_bitmap[g >> 5] |= (1u << (g & 31));
        }
    }
    __syncthreads();

    // --- tail: bitmap -> ascending index list via block prefix scan ---
    unsigned word = s_bitmap[tid >> 1];
    unsigned half = (tid & 1) ? (word >> 16) : (word & 0xFFFFu);
    int cnt = __popc(half);
    int inc = cnt;
    #pragma unroll
    for (int off = 1; off < 64; off <<= 1) {
        int n = __shfl_up(inc, off);
        if (lane >= off) inc += n;
    }
    if (lane == 63) s_wt[wid] = inc;
    __syncthreads();
    int base = inc - cnt;
    for (int w = 0; w < wid; ++w) base += s_wt[w];
    int* sb = sorted_idx + (size_t)b * NSAMP;
    int pos = base;
    #pragma unroll
    for (int k = 0; k < PPT; ++k)
        if ((half >> k) & 1) { sb[pos++] = tid * PPT + k; }
}

// -----------------------------------------------------------------------------
// Gather kernel: one wave per sampled row.
//   out0 = new_xyz [B,S,3]; out1 = concat(xyz, points) [B,S,1,131]; out2 [B,S,128]
// -----------------------------------------------------------------------------
__global__ void gather_kernel(
    const float* __restrict__ xyz, const float* __restrict__ points,
    const float* __restrict__ pres, const int* __restrict__ sorted_idx,
    float* __restrict__ out0, float* __restrict__ out1, float* __restrict__ out2)
{
    int gw   = (int)((blockIdx.x * (unsigned)blockDim.x + threadIdx.x) >> 6);
    int lane = threadIdx.x & 63;
    if (gw >= BATCH * NSAMP) return;
    int b = gw >> 12;               // NSAMP == 4096
    int i = sorted_idx[gw];

    const float* xs = xyz    + ((size_t)b * NPTS + i) * 3;
    const float* ps = points + ((size_t)b * NPTS + i) * 128;
    const float* rs = pres   + ((size_t)b * NPTS + i) * 128;

    if (lane < 3) out0[(size_t)gw * 3 + lane] = xs[lane];

    float* o1 = out1 + (size_t)gw * 131;
    #pragma unroll
    for (int j = 0; j < 3; ++j) {
        int c = lane + 64 * j;
        if (c < 131) o1[c] = (c < 3) ? xs[c] : ps[c - 3];
    }

    const float2* r2 = (const float2*)rs;
    float2* o2 = (float2*)(out2 + (size_t)gw * 128);
    o2[lane] = r2[lane];
}

extern "C" void kernel_launch(void* const* d_in, const int* in_sizes, int n_in,
                              void* d_out, int out_size, void* d_ws, size_t ws_size,
                              hipStream_t stream)
{
    const float* xyz    = (const float*)d_in[0];
    const float* points = (const float*)d_in[1];
    const float* pres   = (const float*)d_in[2];

    float* out  = (float*)d_out;
    float* out0 = out;                                     // B*S*3
    float* out1 = out0 + (size_t)BATCH * NSAMP * 3;        // B*S*131
    float* out2 = out1 + (size_t)BATCH * NSAMP * 131;      // B*S*128

    int* sorted = (int*)d_ws;   // B*S ints = 256 KiB scratch

    fps_kernel<<<BATCH, NTHREADS, 0, stream>>>(xyz, sorted);

    int total_threads = BATCH * NSAMP * 64;   // one wave per sampled row
    int threads = 256;
    int blocks  = total_threads / threads;
    gather_kernel<<<blocks, threads, 0, stream>>>(xyz, points, pres, sorted,
                                                  out0, out1, out2);
}

// Round 3
// 6591.278 us; speedup vs baseline: 1.2699x; 1.0916x over previous
//
#include <hip/hip_runtime.h>

// Problem constants (from setup_inputs: B=16, N=16384, D=128, S=N/4)
#define BATCH    16
#define NPTS     16384
#define NSAMP    4096
#define NTHREADS 512
#define PPT      32      // NPTS / NTHREADS, points per thread (contiguous)

// DPP helper: move with self-preserving old (disabled lanes keep own value)
template<int CTRL, int RM>
__device__ __forceinline__ unsigned dpp_mov(unsigned v) {
    return (unsigned)__builtin_amdgcn_update_dpp((int)v, (int)v, CTRL, RM, 0xF, false);
}

// One step of a (hi,lo) u64-key max reduction via DPP.
// hi = dist bits (non-negative fp32 -> uint order == float order)
// lo = ~global_index (max key => min index on dist ties)
template<int CTRL, int RM>
__device__ __forceinline__ void red_step(unsigned& hi, unsigned& lo) {
    unsigned h2 = dpp_mov<CTRL, RM>(hi);
    unsigned l2 = dpp_mov<CTRL, RM>(lo);
    bool take = (h2 > hi) || (h2 == hi && l2 > lo);
    hi = take ? h2 : hi;
    lo = take ? l2 : lo;
}

// -----------------------------------------------------------------------------
// FPS kernel: one block per batch, 512 threads, 32 points/thread.
// Coordinates are PINNED into VGPRs via an opaque asm (otherwise the compiler
// rematerializes them from global every iteration -- observed VGPR_Count=40
// with 64 declared floats in rounds 1-2).
// Exact reference semantics: dist = min(dist, (x-cx)^2+(y-cy)^2+(z-cz)^2)
// (fp32, no FMA, (xx+yy)+zz association), argmax with first-index tie-break.
// Per iteration: ONE barrier; wave DPP pair-reduce; cross-wave ds_max_u64;
// centroid re-fetched from global (L2-resident) via uniform scalar load.
// -----------------------------------------------------------------------------
__global__ __launch_bounds__(NTHREADS, 2) void fps_kernel(
    const float* __restrict__ xyz, int* __restrict__ sorted_idx)
{
    __shared__ unsigned s_bitmap[NPTS / 32];       // 512 words = 2 KiB
    __shared__ unsigned long long s_slot[4];       // rotating winner slots
    __shared__ int s_wt[NTHREADS / 64];            // tail scan totals

    const int tid  = threadIdx.x;
    const int lane = tid & 63;
    const int wid  = tid >> 6;
    const int b    = blockIdx.x;

    if (tid < NPTS / 32) s_bitmap[tid] = 0u;
    if (tid < 4) s_slot[tid] = 0ull;

    const float* xb = xyz + (size_t)b * NPTS * 3;

    // load this thread's PPT contiguous points into registers, then PIN them
    float px[PPT], py[PPT], pz[PPT], pd[PPT];
    {
        const float* p = xb + (size_t)tid * PPT * 3;
        #pragma unroll
        for (int k = 0; k < PPT; ++k) {
            px[k] = p[3 * k + 0];
            py[k] = p[3 * k + 1];
            pz[k] = p[3 * k + 2];
            pd[k] = 1e10f;   // BIG, matches reference init
        }
    }
    #pragma unroll
    for (int k = 0; k < PPT; ++k) {
        // opaque def: compiler can no longer re-load these from memory
        asm volatile("" : "+v"(px[k]), "+v"(py[k]), "+v"(pz[k]));
    }

    // initial farthest = index 0
    float cx = xb[0], cy = xb[1], cz = xb[2];
    if (tid == 0) s_bitmap[0] = 1u;
    __syncthreads();

    for (int s = 0; s < NSAMP - 1; ++s) {
        // --- phase A: exact distance update + inline per-thread argmax ---
        float bv = -1.0f;
        int   bk = 0;
        #pragma unroll
        for (int k = 0; k < PPT; ++k) {
            float dx = __fsub_rn(px[k], cx);
            float dy = __fsub_rn(py[k], cy);
            float dz = __fsub_rn(pz[k], cz);
            float d  = __fadd_rn(__fadd_rn(__fmul_rn(dx, dx), __fmul_rn(dy, dy)),
                                 __fmul_rn(dz, dz));
            float nd = fminf(pd[k], d);
            pd[k] = nd;
            if (nd > bv) { bv = nd; bk = k; }   // strict > keeps smallest k
        }

        // --- wave-level DPP pair-reduce of the packed key (result in lane 63) ---
        unsigned hi = __float_as_uint(bv);
        unsigned lo = ~(unsigned)(tid * PPT + bk);
        red_step<0x111, 0xF>(hi, lo);   // row_shr:1
        red_step<0x112, 0xF>(hi, lo);   // row_shr:2
        red_step<0x114, 0xF>(hi, lo);   // row_shr:4
        red_step<0x118, 0xF>(hi, lo);   // row_shr:8
        red_step<0x142, 0xA>(hi, lo);   // row_bcast:15 (rows 1,3)
        red_step<0x143, 0xC>(hi, lo);   // row_bcast:31 (rows 2,3)

        if (lane == 63)
            atomicMax(&s_slot[s & 3], ((unsigned long long)hi << 32) | (unsigned long long)lo);

        __syncthreads();   // the ONLY barrier per iteration

        unsigned long long key = s_slot[s & 3];
        unsigned gi = ~(unsigned)key;                      // winner index in [0,NPTS)
        int g = __builtin_amdgcn_readfirstlane((int)gi);   // force SGPR / scalar load

        cx = xb[3 * g + 0];
        cy = xb[3 * g + 1];
        cz = xb[3 * g + 2];

        if (tid == 0) {
            s_slot[(s + 3) & 3] = 0ull;                    // reset slot reused at s+3
            s_bitmap[g >> 5] |= (1u << (g & 31));
        }
    }
    __syncthreads();

    // --- tail: bitmap -> ascending index list via block prefix scan ---
    unsigned word = s_bitmap[tid];        // one 32-bit word per thread
    int cnt = __popc(word);
    int inc = cnt;
    #pragma unroll
    for (int off = 1; off < 64; off <<= 1) {
        int n = __shfl_up(inc, off);
        if (lane >= off) inc += n;
    }
    if (lane == 63) s_wt[wid] = inc;
    __syncthreads();
    int base = inc - cnt;
    for (int w = 0; w < wid; ++w) base += s_wt[w];
    int* sb = sorted_idx + (size_t)b * NSAMP;
    int pos = base;
    unsigned wmask = word;
    while (wmask) {
        int k = __ffs(wmask) - 1;
        wmask &= wmask - 1;
        sb[pos++] = tid * 32 + k;
    }
}

// -----------------------------------------------------------------------------
// Gather kernel: one wave per sampled row.
//   out0 = new_xyz [B,S,3]; out1 = concat(xyz, points) [B,S,1,131]; out2 [B,S,128]
// -----------------------------------------------------------------------------
__global__ void gather_kernel(
    const float* __restrict__ xyz, const float* __restrict__ points,
    const float* __restrict__ pres, const int* __restrict__ sorted_idx,
    float* __restrict__ out0, float* __restrict__ out1, float* __restrict__ out2)
{
    int gw   = (int)((blockIdx.x * (unsigned)blockDim.x + threadIdx.x) >> 6);
    int lane = threadIdx.x & 63;
    if (gw >= BATCH * NSAMP) return;
    int b = gw >> 12;               // NSAMP == 4096
    int i = sorted_idx[gw];

    const float* xs = xyz    + ((size_t)b * NPTS + i) * 3;
    const float* ps = points + ((size_t)b * NPTS + i) * 128;
    const float* rs = pres   + ((size_t)b * NPTS + i) * 128;

    if (lane < 3) out0[(size_t)gw * 3 + lane] = xs[lane];

    float* o1 = out1 + (size_t)gw * 131;
    #pragma unroll
    for (int j = 0; j < 3; ++j) {
        int c = lane + 64 * j;
        if (c < 131) o1[c] = (c < 3) ? xs[c] : ps[c - 3];
    }

    const float2* r2 = (const float2*)rs;
    float2* o2 = (float2*)(out2 + (size_t)gw * 128);
    o2[lane] = r2[lane];
}

extern "C" void kernel_launch(void* const* d_in, const int* in_sizes, int n_in,
                              void* d_out, int out_size, void* d_ws, size_t ws_size,
                              hipStream_t stream)
{
    const float* xyz    = (const float*)d_in[0];
    const float* points = (const float*)d_in[1];
    const float* pres   = (const float*)d_in[2];

    float* out  = (float*)d_out;
    float* out0 = out;                                     // B*S*3
    float* out1 = out0 + (size_t)BATCH * NSAMP * 3;        // B*S*131
    float* out2 = out1 + (size_t)BATCH * NSAMP * 131;      // B*S*128

    int* sorted = (int*)d_ws;   // B*S ints = 256 KiB scratch

    fps_kernel<<<BATCH, NTHREADS, 0, stream>>>(xyz, sorted);

    int total_threads = BATCH * NSAMP * 64;   // one wave per sampled row
    int threads = 256;
    int blocks  = total_threads / threads;
    gather_kernel<<<blocks, threads, 0, stream>>>(xyz, points, pres, sorted,
                                                  out0, out1, out2);
}